// Round 1
// baseline (776.558 us; speedup 1.0000x reference)
//
#include <hip/hip_runtime.h>

#define NDIM 64
#define STRIDE 68          // 64 + 4 pad: keeps 16B alignment, rotates banks by 4/row
#define DT_ 0.01f

// ---------------- device helpers ----------------

__device__ __forceinline__ void copy_g2l(float* dst, const float* __restrict__ src, int tid) {
    // copy 64x64 row-major global -> LDS (stride 68), 4 float4 per thread
#pragma unroll
    for (int i = 0; i < 4; ++i) {
        int idx  = tid + i * 256;        // float4 index 0..1023
        int flat = idx * 4;
        int r = flat >> 6;
        int c = flat & 63;
        *(float4*)&dst[r * STRIDE + c] = *(const float4*)&src[flat];
    }
}

__device__ __forceinline__ void tile_load(float (&t)[4][4], const float* src, int tx, int ty) {
#pragma unroll
    for (int r = 0; r < 4; ++r)
        *(float4*)&t[r][0] = *(const float4*)&src[(4 * ty + r) * STRIDE + 4 * tx];
}

__device__ __forceinline__ void store_tile(float* dst, const float (&v)[4][4], int tx, int ty) {
#pragma unroll
    for (int r = 0; r < 4; ++r)
        *(float4*)&dst[(4 * ty + r) * STRIDE + 4 * tx] = *(const float4*)&v[r][0];
}

// C(4x4 tile) = A @ B   (both row-major in LDS, stride 68). ACC: accumulate into acc.
template <bool ACC>
__device__ __forceinline__ void gemm_nn(const float* A, const float* B,
                                        float (&acc)[4][4], int tx, int ty) {
    if (!ACC) {
#pragma unroll
        for (int r = 0; r < 4; ++r)
#pragma unroll
            for (int c = 0; c < 4; ++c) acc[r][c] = 0.f;
    }
#pragma unroll 2
    for (int k0 = 0; k0 < NDIM; k0 += 4) {
        float a[4][4], bb[4][4];
#pragma unroll
        for (int r = 0; r < 4; ++r)
            *(float4*)&a[r][0] = *(const float4*)&A[(4 * ty + r) * STRIDE + k0];
#pragma unroll
        for (int j = 0; j < 4; ++j)
            *(float4*)&bb[j][0] = *(const float4*)&B[(k0 + j) * STRIDE + 4 * tx];
#pragma unroll
        for (int r = 0; r < 4; ++r)
#pragma unroll
            for (int c = 0; c < 4; ++c)
                acc[r][c] += a[r][0] * bb[0][c] + a[r][1] * bb[1][c] +
                             a[r][2] * bb[2][c] + a[r][3] * bb[3][c];
    }
}

// C(4x4 tile) = A @ B^T  (both row-major in LDS). B^T[k][n] = B[n][k].
template <bool ACC>
__device__ __forceinline__ void gemm_nt(const float* A, const float* B,
                                        float (&acc)[4][4], int tx, int ty) {
    if (!ACC) {
#pragma unroll
        for (int r = 0; r < 4; ++r)
#pragma unroll
            for (int c = 0; c < 4; ++c) acc[r][c] = 0.f;
    }
#pragma unroll 2
    for (int k0 = 0; k0 < NDIM; k0 += 4) {
        float a[4][4], bt[4][4];
#pragma unroll
        for (int r = 0; r < 4; ++r)
            *(float4*)&a[r][0] = *(const float4*)&A[(4 * ty + r) * STRIDE + k0];
#pragma unroll
        for (int c = 0; c < 4; ++c)
            *(float4*)&bt[c][0] = *(const float4*)&B[(4 * tx + c) * STRIDE + k0];
#pragma unroll
        for (int r = 0; r < 4; ++r)
#pragma unroll
            for (int c = 0; c < 4; ++c)
                acc[r][c] += a[r][0] * bt[c][0] + a[r][1] * bt[c][1] +
                             a[r][2] * bt[c][2] + a[r][3] * bt[c][3];
    }
}

// ---------------- setup: P21 = U_one @ (I + W + W^2), W = I - U_half ----------------

__global__ void __launch_bounds__(256) krk_setup(const float* __restrict__ Uh,
                                                 const float* __restrict__ U1,
                                                 float* __restrict__ P21out) {
    __shared__ float sA[NDIM * STRIDE];
    __shared__ float sB[NDIM * STRIDE];
    int tid = threadIdx.x, tx = tid & 15, ty = tid >> 4;

    // W = I - U_half -> sA
#pragma unroll
    for (int i = 0; i < 4; ++i) {
        int idx  = tid + i * 256;
        int flat = idx * 4;
        int r = flat >> 6, c = flat & 63;
        float4 v = *(const float4*)&Uh[flat];
        float w[4] = {-v.x, -v.y, -v.z, -v.w};
#pragma unroll
        for (int j = 0; j < 4; ++j)
            if (r == c + j) w[j] += 1.f;
        *(float4*)&sA[r * STRIDE + c] = *(float4*)w;
    }
    __syncthreads();

    float w2[4][4];
    gemm_nn<false>(sA, sA, w2, tx, ty);          // W^2
    // inv = I + W + W^2 -> sB  (own-tile read of W, own-tile write to sB)
    float tw[4][4];
    tile_load(tw, sA, tx, ty);
    float inv[4][4];
#pragma unroll
    for (int r = 0; r < 4; ++r)
#pragma unroll
        for (int c = 0; c < 4; ++c)
            inv[r][c] = ((4 * ty + r) == (4 * tx + c) ? 1.f : 0.f) + tw[r][c] + w2[r][c];
    store_tile(sB, inv, tx, ty);
    __syncthreads();

    copy_g2l(sA, U1, tid);                        // U_one -> sA (W dead)
    __syncthreads();
    float p[4][4];
    gemm_nn<false>(sA, sB, p, tx, ty);            // P21 = U_one @ inv
#pragma unroll
    for (int r = 0; r < 4; ++r)
        *(float4*)&P21out[(4 * ty + r) * NDIM + 4 * tx] = *(float4*)&p[r][0];
}

// ---------------- main: one workgroup per density matrix ----------------

__global__ void __launch_bounds__(256, 3) krk_main(const float* __restrict__ rho0,
                                                   const float* __restrict__ Uh,
                                                   const float* __restrict__ U1,
                                                   const float* __restrict__ L0,
                                                   const float* __restrict__ Lh,
                                                   const float* __restrict__ L1,
                                                   const float* __restrict__ P21,
                                                   float* __restrict__ out) {
    __shared__ float B0[NDIM * STRIDE];   // rho0 -> E -> rho2
    __shared__ float B1[NDIM * STRIDE];   // rotating scratch (T, X, rho1, S1)
    __shared__ float Sa[NDIM * STRIDE];   // current small operator

    const int tid = threadIdx.x, tx = tid & 15, ty = tid >> 4;
    const size_t b = blockIdx.x;
    const float* rho = rho0 + b * (size_t)(NDIM * NDIM);

    const float c12 = 0.5f * DT_;          // DT/2
    const float c16 = DT_ / 6.f;           // DT/6
    const float c23 = 2.f * DT_ / 3.f;     // 2DT/3

    float t0[4][4], t1[4][4], s0[4][4], s1[4][4], y[4][4], z[4][4], g[4][4], s2[4][4];
    float tile[4][4];

    // ---- load rho0, L0_0
    copy_g2l(B0, rho, tid);
    copy_g2l(Sa, L0, tid);
    __syncthreads();

    // ---- S0 = sum_k L0_k rho0 L0_k^T
    gemm_nn<false>(Sa, B0, t0, tx, ty);            // T = L0_0 @ rho0
    store_tile(B1, t0, tx, ty);
    __syncthreads();
    gemm_nt<false>(B1, Sa, s0, tx, ty);            // S0 = T @ L0_0^T
    __syncthreads();
    copy_g2l(Sa, L0 + 4096, tid);
    __syncthreads();
    gemm_nn<false>(Sa, B0, t0, tx, ty);            // T = L0_1 @ rho0
    store_tile(B1, t0, tx, ty);
    __syncthreads();
    gemm_nt<true>(B1, Sa, s0, tx, ty);             // S0 += T @ L0_1^T
    __syncthreads();

    // ---- X = rho0 + (DT/2) S0 -> B1 ; load U_half
    tile_load(tile, B0, tx, ty);
#pragma unroll
    for (int r = 0; r < 4; ++r)
#pragma unroll
        for (int c = 0; c < 4; ++c) t0[r][c] = tile[r][c] + c12 * s0[r][c];
    store_tile(B1, t0, tx, ty);
    copy_g2l(Sa, Uh, tid);
    __syncthreads();

    // ---- rho1 = U_half X U_half^T
    gemm_nn<false>(Sa, B1, t0, tx, ty);            // T = U_half @ X
    __syncthreads();
    store_tile(B1, t0, tx, ty);
    __syncthreads();
    gemm_nt<false>(B1, Sa, t1, tx, ty);            // rho1 = T @ U_half^T
    __syncthreads();
    store_tile(B1, t1, tx, ty);                    // B1 = rho1
    copy_g2l(Sa, Lh, tid);                         // Lh_0
    __syncthreads();

    // ---- S1 = sum_k Lh_k rho1 Lh_k^T  (rho1 lives in B1, so stage both T's first)
    gemm_nn<false>(Sa, B1, t0, tx, ty);            // T0 = Lh_0 @ rho1 (keep in regs)
    __syncthreads();
    copy_g2l(Sa, Lh + 4096, tid);                  // Lh_1
    __syncthreads();
    gemm_nn<false>(Sa, B1, t1, tx, ty);            // T1 = Lh_1 @ rho1
    __syncthreads();
    store_tile(B1, t1, tx, ty);                    // rho1 dead
    __syncthreads();
    gemm_nt<false>(B1, Sa, s1, tx, ty);            // S1 = T1 @ Lh_1^T
    __syncthreads();
    store_tile(B1, t0, tx, ty);
    copy_g2l(Sa, Lh, tid);                         // reload Lh_0
    __syncthreads();
    gemm_nt<true>(B1, Sa, s1, tx, ty);             // S1 += T0 @ Lh_0^T
    __syncthreads();

    // ---- Y = P21 S1 P21^T
    store_tile(B1, s1, tx, ty);
    copy_g2l(Sa, P21, tid);
    __syncthreads();
    gemm_nn<false>(Sa, B1, t0, tx, ty);            // T = P21 @ S1
    __syncthreads();
    store_tile(B1, t0, tx, ty);
    __syncthreads();
    gemm_nt<false>(B1, Sa, y, tx, ty);             // Y = T @ P21^T
    __syncthreads();

    // ---- Z = U_one rho0 U_one^T
    copy_g2l(Sa, U1, tid);
    __syncthreads();
    gemm_nn<false>(Sa, B0, t0, tx, ty);            // T = U_one @ rho0
    store_tile(B1, t0, tx, ty);
    __syncthreads();
    gemm_nt<false>(B1, Sa, z, tx, ty);             // Z = T @ U_one^T
    __syncthreads();

    // ---- E = rho0 + (DT/6) S0 -> B0 (in place, own tile)
    tile_load(tile, B0, tx, ty);
#pragma unroll
    for (int r = 0; r < 4; ++r)
#pragma unroll
        for (int c = 0; c < 4; ++c) t0[r][c] = tile[r][c] + c16 * s0[r][c];
    store_tile(B0, t0, tx, ty);
    __syncthreads();

    // ---- G = U_one E U_one^T
    gemm_nn<false>(Sa, B0, t0, tx, ty);            // T = U_one @ E
    store_tile(B1, t0, tx, ty);
    __syncthreads();
    gemm_nt<false>(B1, Sa, g, tx, ty);             // G = T @ U_one^T
    __syncthreads();

    // ---- rho2 = Z + DT*Y -> B0 ; load L1_0
#pragma unroll
    for (int r = 0; r < 4; ++r)
#pragma unroll
        for (int c = 0; c < 4; ++c) t0[r][c] = z[r][c] + DT_ * y[r][c];
    store_tile(B0, t0, tx, ty);
    copy_g2l(Sa, L1, tid);
    __syncthreads();

    // ---- S2 = sum_k L1_k rho2 L1_k^T
    gemm_nn<false>(Sa, B0, t0, tx, ty);            // T = L1_0 @ rho2
    store_tile(B1, t0, tx, ty);
    __syncthreads();
    gemm_nt<false>(B1, Sa, s2, tx, ty);            // S2 = T @ L1_0^T
    __syncthreads();
    copy_g2l(Sa, L1 + 4096, tid);
    __syncthreads();
    gemm_nn<false>(Sa, B0, t0, tx, ty);            // T = L1_1 @ rho2
    store_tile(B1, t0, tx, ty);
    __syncthreads();
    gemm_nt<true>(B1, Sa, s2, tx, ty);             // S2 += T @ L1_1^T

    // ---- out = G + (2DT/3) Y + (DT/6) S2
    float* o = out + b * (size_t)(NDIM * NDIM);
#pragma unroll
    for (int r = 0; r < 4; ++r) {
        float4 v;
        v.x = g[r][0] + c23 * y[r][0] + c16 * s2[r][0];
        v.y = g[r][1] + c23 * y[r][1] + c16 * s2[r][1];
        v.z = g[r][2] + c23 * y[r][2] + c16 * s2[r][2];
        v.w = g[r][3] + c23 * y[r][3] + c16 * s2[r][3];
        *(float4*)&o[(4 * ty + r) * NDIM + 4 * tx] = v;
    }
}

// ---------------- host launch ----------------

extern "C" void kernel_launch(void* const* d_in, const int* in_sizes, int n_in,
                              void* d_out, int out_size, void* d_ws, size_t ws_size,
                              hipStream_t stream) {
    const float* rho0 = (const float*)d_in[0];
    const float* Uh   = (const float*)d_in[1];
    const float* U1   = (const float*)d_in[2];
    const float* L0   = (const float*)d_in[3];
    const float* Lh   = (const float*)d_in[4];
    const float* L1   = (const float*)d_in[5];
    float* out = (float*)d_out;
    float* P21 = (float*)d_ws;             // 64*64 floats = 16 KB scratch

    int Bn = in_sizes[0] / (NDIM * NDIM);  // 4096

    krk_setup<<<1, 256, 0, stream>>>(Uh, U1, P21);
    krk_main<<<Bn, 256, 0, stream>>>(rho0, Uh, U1, L0, Lh, L1, P21, out);
}

// Round 2
// 198.328 us; speedup vs baseline: 3.9155x; 3.9155x over previous
//
#include <hip/hip_runtime.h>
#include <hip/hip_bf16.h>

#define NDIM 64
#define DT_  0.01f
#define FP   68    // fp32 LDS pitch (setup kernel only)
#define BP   72    // bf16 LDS pitch (main kernel): 36 words == 4 mod 32 -> b128 frag reads phase-conflict-free

typedef __attribute__((ext_vector_type(8))) short bf16x8;
typedef __attribute__((ext_vector_type(4))) float f32x4;

// ---------------- scalar bf16 helpers ----------------

__device__ __forceinline__ unsigned short f2b(float x) {
    __hip_bfloat16 h = __float2bfloat16(x);          // RTNE
    return __builtin_bit_cast(unsigned short, h);
}
__device__ __forceinline__ float b2f(unsigned short u) {
    unsigned int v = (unsigned int)u << 16;
    return __builtin_bit_cast(float, v);
}

// ---------------- fp32 helpers (setup kernel only) ----------------

__device__ __forceinline__ void s_copy_g2l(float* dst, const float* __restrict__ src, int tid) {
#pragma unroll
    for (int i = 0; i < 4; ++i) {
        int idx  = tid + i * 256;
        int flat = idx * 4;
        int r = flat >> 6, c = flat & 63;
        *(float4*)&dst[r * FP + c] = *(const float4*)&src[flat];
    }
}

__device__ __forceinline__ void s_gemm_nn(const float* A, const float* B,
                                          float (&acc)[4][4], int tx, int ty) {
#pragma unroll
    for (int r = 0; r < 4; ++r)
#pragma unroll
        for (int c = 0; c < 4; ++c) acc[r][c] = 0.f;
#pragma unroll 2
    for (int k0 = 0; k0 < NDIM; k0 += 4) {
        float a[4][4], bb[4][4];
#pragma unroll
        for (int r = 0; r < 4; ++r)
            *(float4*)&a[r][0] = *(const float4*)&A[(4 * ty + r) * FP + k0];
#pragma unroll
        for (int j = 0; j < 4; ++j)
            *(float4*)&bb[j][0] = *(const float4*)&B[(k0 + j) * FP + 4 * tx];
#pragma unroll
        for (int r = 0; r < 4; ++r)
#pragma unroll
            for (int c = 0; c < 4; ++c)
                acc[r][c] += a[r][0] * bb[0][c] + a[r][1] * bb[1][c] +
                             a[r][2] * bb[2][c] + a[r][3] * bb[3][c];
    }
}

// ---------------- setup: P21 = U1 @ (I + W + W^2), W = I - Uh; cast 9 operators to bf16 in ws ----
// ws layout (bf16, 4096 elems each): 0=Uh 1=U1 2=L0_0 3=L0_1 4=Lh_0 5=Lh_1 6=L1_0 7=L1_1 8=P21

__global__ void __launch_bounds__(256) krk_setup(const float* __restrict__ Uh,
                                                 const float* __restrict__ U1,
                                                 const float* __restrict__ L0,
                                                 const float* __restrict__ Lh,
                                                 const float* __restrict__ L1,
                                                 unsigned short* __restrict__ ws) {
    __shared__ float sA[NDIM * FP];
    __shared__ float sB[NDIM * FP];
    int tid = threadIdx.x, tx = tid & 15, ty = tid >> 4;

    // W = I - Uh -> sA
#pragma unroll
    for (int i = 0; i < 4; ++i) {
        int idx  = tid + i * 256;
        int flat = idx * 4;
        int r = flat >> 6, c = flat & 63;
        float4 v = *(const float4*)&Uh[flat];
        float w[4] = {-v.x, -v.y, -v.z, -v.w};
#pragma unroll
        for (int j = 0; j < 4; ++j)
            if (r == c + j) w[j] += 1.f;
        *(float4*)&sA[r * FP + c] = *(float4*)w;
    }
    __syncthreads();

    float w2[4][4];
    s_gemm_nn(sA, sA, w2, tx, ty);                 // W^2
    float inv[4][4];
#pragma unroll
    for (int r = 0; r < 4; ++r)
#pragma unroll
        for (int c = 0; c < 4; ++c) {
            float wv = sA[(4 * ty + r) * FP + 4 * tx + c];
            inv[r][c] = ((4 * ty + r) == (4 * tx + c) ? 1.f : 0.f) + wv + w2[r][c];
        }
    __syncthreads();
#pragma unroll
    for (int r = 0; r < 4; ++r)
        *(float4*)&sB[(4 * ty + r) * FP + 4 * tx] = *(float4*)&inv[r][0];
    __syncthreads();

    s_copy_g2l(sA, U1, tid);                        // U1 -> sA
    __syncthreads();
    float p[4][4];
    s_gemm_nn(sA, sB, p, tx, ty);                   // P21
#pragma unroll
    for (int r = 0; r < 4; ++r) {
        unsigned short o[4] = {f2b(p[r][0]), f2b(p[r][1]), f2b(p[r][2]), f2b(p[r][3])};
        *(uint2*)&ws[8 * 4096 + (4 * ty + r) * 64 + 4 * tx] = *(uint2*)o;
    }

    // cast 8 input operator matrices
    const float* srcs[8] = {Uh, U1, L0, L0 + 4096, Lh, Lh + 4096, L1, L1 + 4096};
#pragma unroll
    for (int m = 0; m < 8; ++m) {
        const float* s = srcs[m];
        unsigned short* d = ws + m * 4096;
#pragma unroll
        for (int i = 0; i < 4; ++i) {
            int flat = (tid + i * 256) * 4;
            float4 v = *(const float4*)&s[flat];
            unsigned short o[4] = {f2b(v.x), f2b(v.y), f2b(v.z), f2b(v.w)};
            *(uint2*)&d[flat] = *(uint2*)o;
        }
    }
}

// ---------------- main-kernel LDS staging ----------------

__device__ __forceinline__ void g2l_f32(unsigned short* dst, const float* __restrict__ src, int tid) {
#pragma unroll
    for (int i = 0; i < 4; ++i) {
        int id = tid + i * 256;
        int flat = id * 4;
        int r = flat >> 6, c = flat & 63;
        float4 v = *(const float4*)&src[flat];
        unsigned short o[4] = {f2b(v.x), f2b(v.y), f2b(v.z), f2b(v.w)};
        *(uint2*)&dst[r * BP + c] = *(uint2*)o;     // 8B, aligned (c % 4 == 0)
    }
}

__device__ __forceinline__ void g2l_b16(unsigned short* dst, const unsigned short* __restrict__ src, int tid) {
#pragma unroll
    for (int i = 0; i < 2; ++i) {
        int id = tid + i * 256;
        int flat = id * 8;
        int r = flat >> 6, c = flat & 63;
        *(uint4*)&dst[r * BP + c] = *(const uint4*)&src[flat];   // 16B, aligned (c % 8 == 0)
    }
}

// ---------------- MFMA NT gemm: C(16x64 stripe of wave w) = A @ B^T, A,B row-major bf16 LDS ----

__device__ __forceinline__ bf16x8 ldfrag(const unsigned short* M, int rb, int k0, int c, int q) {
    return *(const bf16x8*)&M[(rb + c) * BP + q * 8 + k0];
}

template <bool ACC>
__device__ __forceinline__ void ntgemm(const unsigned short* A, const unsigned short* Bm,
                                       f32x4 (&acc)[4], int w, int c, int q) {
    bf16x8 a0 = ldfrag(A, 16 * w, 0, c, q);
    bf16x8 a1 = ldfrag(A, 16 * w, 32, c, q);
#pragma unroll
    for (int t = 0; t < 4; ++t) {
        bf16x8 b0 = ldfrag(Bm, 16 * t, 0, c, q);
        bf16x8 b1 = ldfrag(Bm, 16 * t, 32, c, q);
        f32x4 a = ACC ? acc[t] : (f32x4){0.f, 0.f, 0.f, 0.f};
        a = __builtin_amdgcn_mfma_f32_16x16x32_bf16(a0, b0, a, 0, 0, 0);
        a = __builtin_amdgcn_mfma_f32_16x16x32_bf16(a1, b1, a, 0, 0, 0);
        acc[t] = a;
    }
}

// write wave stripe (C layout: row = 16w+4q+i, col = 16t+c) to LDS bf16
__device__ __forceinline__ void st_stripe(unsigned short* D, const f32x4 (&v)[4], int w, int c, int q) {
#pragma unroll
    for (int t = 0; t < 4; ++t)
#pragma unroll
        for (int i = 0; i < 4; ++i)
            D[(16 * w + 4 * q + i) * BP + 16 * t + c] = f2b(v[t][i]);
}

// ---------------- main: one workgroup per density matrix ----------------

__global__ void __launch_bounds__(256) krk_main(const float* __restrict__ rho0,
                                                const unsigned short* __restrict__ ws,
                                                float* __restrict__ out) {
    __shared__ unsigned short B0[NDIM * BP];   // rho0 -> E -> rho2
    __shared__ unsigned short B1[NDIM * BP];   // rotating scratch
    __shared__ unsigned short Sa[NDIM * BP];   // current operator

    const int tid = threadIdx.x;
    const int w = tid >> 6, lane = tid & 63, q = lane >> 4, c = lane & 15;
    const float* rho = rho0 + (size_t)blockIdx.x * (NDIM * NDIM);

    const float c12 = 0.5f * DT_, c16 = DT_ / 6.f, c23 = 2.f * DT_ / 3.f;

    f32x4 s0[4], s1[4], y[4], z[4], g[4], s2[4], t[4];

    const unsigned short* W_UH  = ws + 0 * 4096;
    const unsigned short* W_U1  = ws + 1 * 4096;
    const unsigned short* W_L00 = ws + 2 * 4096;
    const unsigned short* W_L01 = ws + 3 * 4096;
    const unsigned short* W_LH0 = ws + 4 * 4096;
    const unsigned short* W_LH1 = ws + 5 * 4096;
    const unsigned short* W_L10 = ws + 6 * 4096;
    const unsigned short* W_L11 = ws + 7 * 4096;
    const unsigned short* W_P21 = ws + 8 * 4096;

    g2l_f32(B0, rho, tid);
    g2l_b16(Sa, W_L00, tid);
    __syncthreads();

    // ---- S0 = sum_k L0_k rho0 L0_k^T  (rho0 symmetric -> all NT)
    ntgemm<false>(Sa, B0, t, w, c, q);            // T = L00 @ rho0
    st_stripe(B1, t, w, c, q);                    // B1 fresh, no prior readers
    __syncthreads();
    ntgemm<false>(B1, Sa, s0, w, c, q);           // S0 = T @ L00^T
    __syncthreads();
    g2l_b16(Sa, W_L01, tid);
    __syncthreads();
    ntgemm<false>(Sa, B0, t, w, c, q);            // T = L01 @ rho0
    st_stripe(B1, t, w, c, q);
    __syncthreads();
    ntgemm<true>(B1, Sa, s0, w, c, q);            // S0 += T @ L01^T
    __syncthreads();

    // ---- X = rho0 + (DT/2) S0 -> B1 ; Sa <- Uh
#pragma unroll
    for (int tt = 0; tt < 4; ++tt)
#pragma unroll
        for (int i = 0; i < 4; ++i) {
            int r = 16 * w + 4 * q + i, cc = 16 * tt + c;
            B1[r * BP + cc] = f2b(b2f(B0[r * BP + cc]) + c12 * s0[tt][i]);
        }
    g2l_b16(Sa, W_UH, tid);
    __syncthreads();

    // ---- rho1 = Uh X Uh^T
    ntgemm<false>(Sa, B1, t, w, c, q);            // T = Uh @ X
    __syncthreads();
    st_stripe(B1, t, w, c, q);
    __syncthreads();
    ntgemm<false>(B1, Sa, t, w, c, q);            // rho1 = T @ Uh^T
    __syncthreads();
    st_stripe(B1, t, w, c, q);                    // B1 = rho1
    g2l_b16(Sa, W_LH0, tid);                      // Sa(Uh) readers done (sync above)
    __syncthreads();

    // ---- S1 = sum_k Lh_k rho1 Lh_k^T
    ntgemm<false>(Sa, B1, t, w, c, q);            // t = Lh0 @ rho1 (persist)
    __syncthreads();
    g2l_b16(Sa, W_LH1, tid);
    __syncthreads();
    ntgemm<false>(Sa, B1, y, w, c, q);            // y(temp) = Lh1 @ rho1
    __syncthreads();                              // rho1 dead
    st_stripe(B1, y, w, c, q);
    __syncthreads();
    ntgemm<false>(B1, Sa, s1, w, c, q);           // S1 = (Lh1 rho1) @ Lh1^T
    __syncthreads();
    st_stripe(B1, t, w, c, q);                    // B1 = Lh0 rho1
    g2l_b16(Sa, W_LH0, tid);
    __syncthreads();
    ntgemm<true>(B1, Sa, s1, w, c, q);            // S1 += (Lh0 rho1) @ Lh0^T
    __syncthreads();

    // ---- Y = P21 S1 P21^T
    st_stripe(B1, s1, w, c, q);
    g2l_b16(Sa, W_P21, tid);
    __syncthreads();
    ntgemm<false>(Sa, B1, t, w, c, q);            // T = P21 @ S1
    __syncthreads();
    st_stripe(B1, t, w, c, q);
    __syncthreads();
    ntgemm<false>(B1, Sa, y, w, c, q);            // Y = T @ P21^T
    __syncthreads();

    // ---- Z = U1 rho0 U1^T
    g2l_b16(Sa, W_U1, tid);
    __syncthreads();
    ntgemm<false>(Sa, B0, t, w, c, q);            // T = U1 @ rho0
    st_stripe(B1, t, w, c, q);                    // B1 readers done (sync above)
    __syncthreads();
    ntgemm<false>(B1, Sa, z, w, c, q);            // Z = T @ U1^T
    __syncthreads();

    // ---- E = rho0 + (DT/6) S0 -> B0 in place (own positions only)
#pragma unroll
    for (int tt = 0; tt < 4; ++tt)
#pragma unroll
        for (int i = 0; i < 4; ++i) {
            int r = 16 * w + 4 * q + i, cc = 16 * tt + c;
            B0[r * BP + cc] = f2b(b2f(B0[r * BP + cc]) + c16 * s0[tt][i]);
        }
    __syncthreads();

    // ---- G = U1 E U1^T
    ntgemm<false>(Sa, B0, t, w, c, q);            // T = U1 @ E
    st_stripe(B1, t, w, c, q);                    // B1 readers done (z-gemm synced)
    __syncthreads();
    ntgemm<false>(B1, Sa, g, w, c, q);            // G = T @ U1^T
    __syncthreads();

    // ---- rho2 = Z + DT*Y -> B0 ; Sa <- L1_0
#pragma unroll
    for (int tt = 0; tt < 4; ++tt)
#pragma unroll
        for (int i = 0; i < 4; ++i) {
            int r = 16 * w + 4 * q + i, cc = 16 * tt + c;
            B0[r * BP + cc] = f2b(z[tt][i] + DT_ * y[tt][i]);
        }
    g2l_b16(Sa, W_L10, tid);
    __syncthreads();

    // ---- S2 = sum_k L1_k rho2 L1_k^T
    ntgemm<false>(Sa, B0, t, w, c, q);            // T = L10 @ rho2
    st_stripe(B1, t, w, c, q);                    // B1 readers done (g-gemm synced)
    __syncthreads();
    ntgemm<false>(B1, Sa, s2, w, c, q);           // S2 = T @ L10^T
    __syncthreads();
    g2l_b16(Sa, W_L11, tid);
    __syncthreads();
    ntgemm<false>(Sa, B0, t, w, c, q);            // T = L11 @ rho2
    st_stripe(B1, t, w, c, q);
    __syncthreads();
    ntgemm<true>(B1, Sa, s2, w, c, q);            // S2 += T @ L11^T

    // ---- out = G + (2DT/3) Y + (DT/6) S2  (fp32 global)
    float* o = out + (size_t)blockIdx.x * (NDIM * NDIM);
#pragma unroll
    for (int tt = 0; tt < 4; ++tt)
#pragma unroll
        for (int i = 0; i < 4; ++i) {
            int r = 16 * w + 4 * q + i, cc = 16 * tt + c;
            o[r * 64 + cc] = g[tt][i] + c23 * y[tt][i] + c16 * s2[tt][i];
        }
}

// ---------------- host launch ----------------

extern "C" void kernel_launch(void* const* d_in, const int* in_sizes, int n_in,
                              void* d_out, int out_size, void* d_ws, size_t ws_size,
                              hipStream_t stream) {
    const float* rho0 = (const float*)d_in[0];
    const float* Uh   = (const float*)d_in[1];
    const float* U1   = (const float*)d_in[2];
    const float* L0   = (const float*)d_in[3];
    const float* Lh   = (const float*)d_in[4];
    const float* L1   = (const float*)d_in[5];
    float* out = (float*)d_out;
    unsigned short* ws = (unsigned short*)d_ws;   // 9 bf16 64x64 matrices = 73728 B

    int Bn = in_sizes[0] / (NDIM * NDIM);         // 4096

    krk_setup<<<1, 256, 0, stream>>>(Uh, U1, L0, Lh, L1, ws);
    krk_main<<<Bn, 256, 0, stream>>>(rho0, ws, out);
}

// Round 3
// 187.738 us; speedup vs baseline: 4.1364x; 1.0564x over previous
//
#include <hip/hip_runtime.h>
#include <hip/hip_bf16.h>

#define NDIM 64
#define BP   72      // bf16 LDS pitch: rows 16B-aligned (144 B), b128 frag reads conflict-free
#define DT_  0.01f

typedef __attribute__((ext_vector_type(8)))  short bf16x8;
typedef __attribute__((ext_vector_type(16))) float f32x16;

struct Frag { bf16x8 f[4]; };

// ---------------- scalar bf16 helpers ----------------

__device__ __forceinline__ unsigned short f2b(float x) {
    __hip_bfloat16 h = __float2bfloat16(x);          // RTNE
    return __builtin_bit_cast(unsigned short, h);
}
__device__ __forceinline__ float b2f(unsigned short u) {
    unsigned int v = (unsigned int)u << 16;
    return __builtin_bit_cast(float, v);
}

// ---------------- fragment / tile helpers (32x32x16 MFMA) ----------------
// Wave w: rw = 32*(w>>1) row block, cw = 32*(w&1) col block.
// A/B frag: lane holds M[rb + (lane&31)][j*16 + (lane>>5)*8 + 0..7]  (one b128)
// C/D layout: col = cw + (lane&31), row = rw + (reg&3) + 8*(reg>>2) + 4*(lane>>5)

__device__ __forceinline__ bf16x8 ldfrag(const unsigned short* M, int rb, int j, int ln, int hq) {
    return *(const bf16x8*)&M[(rb + ln) * BP + j * 16 + hq * 8];
}

__device__ __forceinline__ void ldg_op(Frag& F, const unsigned short* __restrict__ p,
                                       int ln, int hq, int cw) {
#pragma unroll
    for (int j = 0; j < 4; ++j)
        F.f[j] = *(const bf16x8*)&p[(cw + ln) * 64 + j * 16 + hq * 8];
}

// C = A @ Bm^T  (A rows rb from LDS, Bm frags preloaded)
template <bool ACC>
__device__ __forceinline__ void ntg(const unsigned short* A, const Frag& F, f32x16& acc,
                                    int ln, int hq, int rb) {
    if (!ACC) {
#pragma unroll
        for (int r = 0; r < 16; ++r) acc[r] = 0.f;
    }
#pragma unroll
    for (int j = 0; j < 4; ++j)
        acc = __builtin_amdgcn_mfma_f32_32x32x16_bf16(ldfrag(A, rb, j, ln, hq), F.f[j], acc, 0, 0, 0);
}

// two GEMMs sharing A-frags
__device__ __forceinline__ void ntg2(const unsigned short* A, const Frag& Fa, const Frag& Fb,
                                     f32x16& c0, f32x16& c1, int ln, int hq, int rb) {
#pragma unroll
    for (int r = 0; r < 16; ++r) { c0[r] = 0.f; c1[r] = 0.f; }
#pragma unroll
    for (int j = 0; j < 4; ++j) {
        bf16x8 a = ldfrag(A, rb, j, ln, hq);
        c0 = __builtin_amdgcn_mfma_f32_32x32x16_bf16(a, Fa.f[j], c0, 0, 0, 0);
        c1 = __builtin_amdgcn_mfma_f32_32x32x16_bf16(a, Fb.f[j], c1, 0, 0, 0);
    }
}

// transposed store: slot (row,col) -> LDS[col][row]; vector b64 writes
__device__ __forceinline__ void stT(unsigned short* D, const f32x16& v,
                                    int ln, int hq, int rw, int cw) {
#pragma unroll
    for (int g = 0; g < 4; ++g) {
        unsigned short o[4];
#pragma unroll
        for (int j = 0; j < 4; ++j) o[j] = f2b(v[4 * g + j]);
        *(uint2*)&D[(cw + ln) * BP + rw + 8 * g + 4 * hq] = *(uint2*)o;
    }
}

// transposed read into slot order (valid representation for symmetric source)
__device__ __forceinline__ void ldT(float* r, const unsigned short* S,
                                    int ln, int hq, int rw, int cw) {
#pragma unroll
    for (int g = 0; g < 4; ++g) {
        uint2 u = *(const uint2*)&S[(cw + ln) * BP + rw + 8 * g + 4 * hq];
        unsigned short o[4];
        *(uint2*)o = u;
#pragma unroll
        for (int j = 0; j < 4; ++j) r[4 * g + j] = b2f(o[j]);
    }
}

// global fp32 -> LDS bf16 row-major staging
__device__ __forceinline__ void g2l_f32(unsigned short* dst, const float* __restrict__ src, int tid) {
#pragma unroll
    for (int i = 0; i < 4; ++i) {
        int flat = (tid + i * 256) * 4;
        int r = flat >> 6, c = flat & 63;
        float4 v = *(const float4*)&src[flat];
        unsigned short o[4] = {f2b(v.x), f2b(v.y), f2b(v.z), f2b(v.w)};
        *(uint2*)&dst[r * BP + c] = *(uint2*)o;
    }
}

// ---------------- setup: 9 blocks. 0-7 cast operators to bf16; 8 computes P21 ----------------
// ws layout (bf16, 4096 each): 0=Uh 1=U1 2=L00 3=L01 4=Lh0 5=Lh1 6=L10 7=L11 8=P21

__global__ void __launch_bounds__(256) krk_setup(const float* __restrict__ Uh,
                                                 const float* __restrict__ U1,
                                                 const float* __restrict__ L0,
                                                 const float* __restrict__ Lh,
                                                 const float* __restrict__ L1,
                                                 unsigned short* __restrict__ ws) {
    __shared__ unsigned short W [NDIM * BP];
    __shared__ unsigned short Wt[NDIM * BP];
    __shared__ unsigned short Ub[NDIM * BP];
    __shared__ unsigned short BV[NDIM * BP];

    const int blk = blockIdx.x, tid = threadIdx.x;

    if (blk < 8) {
        const float* srcs[8] = {Uh, U1, L0, L0 + 4096, Lh, Lh + 4096, L1, L1 + 4096};
        const float* s = srcs[blk];
        unsigned short* d = ws + blk * 4096;
#pragma unroll
        for (int i = 0; i < 4; ++i) {
            int flat = (tid + i * 256) * 4;
            float4 v = *(const float4*)&s[flat];
            unsigned short o[4] = {f2b(v.x), f2b(v.y), f2b(v.z), f2b(v.w)};
            *(uint2*)&d[flat] = *(uint2*)o;
        }
        return;
    }

    // ---- block 8: P21 = U1 @ (I + W + W^2), W = I - Uh
    const int lane = tid & 63, w = tid >> 6, ln = lane & 31, hq = lane >> 5;
    const int rw = 32 * (w >> 1), cw = 32 * (w & 1);

#pragma unroll
    for (int i = 0; i < 4; ++i) {
        int flat = (tid + i * 256) * 4;
        int r = flat >> 6, c = flat & 63;
        float4 u = *(const float4*)&Uh[flat];
        float wv[4] = {-u.x, -u.y, -u.z, -u.w};
#pragma unroll
        for (int j = 0; j < 4; ++j)
            if (r == c + j) wv[j] += 1.f;
        unsigned short o[4] = {f2b(wv[0]), f2b(wv[1]), f2b(wv[2]), f2b(wv[3])};
        *(uint2*)&W[r * BP + c] = *(uint2*)o;
#pragma unroll
        for (int j = 0; j < 4; ++j) Wt[(c + j) * BP + r] = o[j];
        float4 v = *(const float4*)&U1[flat];
        unsigned short p[4] = {f2b(v.x), f2b(v.y), f2b(v.z), f2b(v.w)};
        *(uint2*)&Ub[r * BP + c] = *(uint2*)p;
    }
    __syncthreads();

    // W2 = W @ (Wt)^T = W @ W   (slot = W2[row][col])
    f32x16 w2;
#pragma unroll
    for (int r = 0; r < 16; ++r) w2[r] = 0.f;
#pragma unroll
    for (int j = 0; j < 4; ++j)
        w2 = __builtin_amdgcn_mfma_f32_32x32x16_bf16(ldfrag(W, rw, j, ln, hq),
                                                     ldfrag(Wt, cw, j, ln, hq), w2, 0, 0, 0);
    // V = I + W + W2 in slots; W[row][col] = Wt[col][row] via ldT
    float wv[16];
    ldT(wv, Wt, ln, hq, rw, cw);
    f32x16 V;
#pragma unroll
    for (int r = 0; r < 16; ++r) {
        int row = rw + (r & 3) + 8 * (r >> 2) + 4 * hq;
        V[r] = ((row == cw + ln) ? 1.f : 0.f) + wv[r] + w2[r];
    }
    stT(BV, V, ln, hq, rw, cw);        // BV row-major = V^T
    __syncthreads();

    // P21 = U1 @ (V^T)^T = U1 @ V   (slot = P21[row][col])
    f32x16 p;
#pragma unroll
    for (int r = 0; r < 16; ++r) p[r] = 0.f;
#pragma unroll
    for (int j = 0; j < 4; ++j)
        p = __builtin_amdgcn_mfma_f32_32x32x16_bf16(ldfrag(Ub, rw, j, ln, hq),
                                                    ldfrag(BV, cw, j, ln, hq), p, 0, 0, 0);
    unsigned short* ws8 = ws + 8 * 4096;
#pragma unroll
    for (int r = 0; r < 16; ++r) {
        int row = rw + (r & 3) + 8 * (r >> 2) + 4 * hq;
        ws8[row * 64 + cw + ln] = f2b(p[r]);
    }
}

// ---------------- main: one workgroup per density matrix ----------------
// Every sandwich M X M^T:  R = ntg(A=X, B=M) = X@M^T, store R^T;
//                          S = ntg(A=R^T, B=M) = (M R)^T, stored via stT -> row-major M R. All NT.

__global__ void __launch_bounds__(256) krk_main(const float* __restrict__ rho0,
                                                const unsigned short* __restrict__ ws,
                                                float* __restrict__ out) {
    __shared__ unsigned short B0[NDIM * BP];
    __shared__ unsigned short B1[NDIM * BP];
    __shared__ unsigned short B2[NDIM * BP];
    __shared__ unsigned short B3[NDIM * BP];

    const int tid = threadIdx.x;
    const int w = tid >> 6, lane = tid & 63, ln = lane & 31, hq = lane >> 5;
    const int rw = 32 * (w >> 1), cw = 32 * (w & 1);
    const float* rho = rho0 + (size_t)blockIdx.x * (NDIM * NDIM);

    const float c12 = 0.5f * DT_, c16 = DT_ / 6.f, c23 = 2.f * DT_ / 3.f;

    f32x16 t0, t1, s0, s1, y, z, g, s2;
    Frag Fa, Fb, Fu;

    // P0: stage rho0 (fp32 -> bf16, row-major; rho0 symmetric)
    g2l_f32(B0, rho, tid);
    __syncthreads();

    // P1: R0 = rho0@L00^T -> B1^T ; R1 = rho0@L01^T -> B2^T
    ldg_op(Fa, ws + 2 * 4096, ln, hq, cw);        // L00
    ldg_op(Fb, ws + 3 * 4096, ln, hq, cw);        // L01
    ntg2(B0, Fa, Fb, t0, t1, ln, hq, rw);
    stT(B1, t0, ln, hq, rw, cw);
    stT(B2, t1, ln, hq, rw, cw);
    __syncthreads();

    // P2: s0 = (L00 R0 + L01 R1)^T slots ; X = rho0 + c12*S0 -> B3 (row-major X)
    ntg<false>(B1, Fa, s0, ln, hq, rw);
    ntg<true >(B2, Fb, s0, ln, hq, rw);
    {
        float r0[16];
        ldT(r0, B0, ln, hq, rw, cw);              // rho0 slots (symmetric)
        f32x16 X;
#pragma unroll
        for (int r = 0; r < 16; ++r) X[r] = r0[r] + c12 * s0[r];
        stT(B3, X, ln, hq, rw, cw);
    }
    ldg_op(Fu, ws + 0 * 4096, ln, hq, cw);        // Uh (prefetch)
    __syncthreads();

    // P3: Rh = X@Uh^T -> B1^T
    ntg<false>(B3, Fu, t0, ln, hq, rw);
    stT(B1, t0, ln, hq, rw, cw);
    __syncthreads();

    // P4: rho1 = (Uh Rh) -> B2 row-major
    ntg<false>(B1, Fu, t1, ln, hq, rw);
    stT(B2, t1, ln, hq, rw, cw);
    ldg_op(Fa, ws + 4 * 4096, ln, hq, cw);        // Lh0 (prefetch)
    ldg_op(Fb, ws + 5 * 4096, ln, hq, cw);        // Lh1
    __syncthreads();

    // P5: Ra = rho1@Lh0^T -> B1^T ; Rb = rho1@Lh1^T -> B3^T
    ntg2(B2, Fa, Fb, t0, t1, ln, hq, rw);
    stT(B1, t0, ln, hq, rw, cw);
    stT(B3, t1, ln, hq, rw, cw);
    __syncthreads();

    // P6: s1 = (Lh0 Ra + Lh1 Rb)^T slots ; store S1 -> B2
    ntg<false>(B1, Fa, s1, ln, hq, rw);
    ntg<true >(B3, Fb, s1, ln, hq, rw);
    stT(B2, s1, ln, hq, rw, cw);
    ldg_op(Fa, ws + 8 * 4096, ln, hq, cw);        // P21 (prefetch)
    __syncthreads();

    // P7: Ry = S1@P21^T -> B1^T
    ntg<false>(B2, Fa, t0, ln, hq, rw);
    stT(B1, t0, ln, hq, rw, cw);
    __syncthreads();

    // P8: y = (P21 Ry)^T slots ; Rz = rho0@U1^T -> B3^T
    ntg<false>(B1, Fa, y, ln, hq, rw);
    ldg_op(Fu, ws + 1 * 4096, ln, hq, cw);        // U1
    ntg<false>(B0, Fu, t1, ln, hq, rw);
    stT(B3, t1, ln, hq, rw, cw);
    __syncthreads();

    // P9: z = (U1 Rz)^T slots ; E = rho0 + c16*S0 -> B1
    ntg<false>(B3, Fu, z, ln, hq, rw);
    {
        float r0[16];
        ldT(r0, B0, ln, hq, rw, cw);
        f32x16 E;
#pragma unroll
        for (int r = 0; r < 16; ++r) E[r] = r0[r] + c16 * s0[r];
        stT(B1, E, ln, hq, rw, cw);
    }
    __syncthreads();

    // P10: Rg = E@U1^T -> B2^T
    ntg<false>(B1, Fu, t0, ln, hq, rw);
    stT(B2, t0, ln, hq, rw, cw);
    __syncthreads();

    // P11: g = (U1 Rg)^T slots ; rho2 = Z + DT*Y -> B3
    ntg<false>(B2, Fu, g, ln, hq, rw);
    {
        f32x16 r2;
#pragma unroll
        for (int r = 0; r < 16; ++r) r2[r] = z[r] + DT_ * y[r];
        stT(B3, r2, ln, hq, rw, cw);
    }
    ldg_op(Fa, ws + 6 * 4096, ln, hq, cw);        // L10 (prefetch)
    ldg_op(Fb, ws + 7 * 4096, ln, hq, cw);        // L11
    __syncthreads();

    // P12: Rc = rho2@L10^T -> B0^T (rho0 dead) ; Rd = rho2@L11^T -> B1^T
    ntg2(B3, Fa, Fb, t0, t1, ln, hq, rw);
    stT(B0, t0, ln, hq, rw, cw);
    stT(B1, t1, ln, hq, rw, cw);
    __syncthreads();

    // P13: s2 = (L10 Rc + L11 Rd)^T slots ; out = G + c23*Y + c16*S2
    ntg<false>(B0, Fa, s2, ln, hq, rw);
    ntg<true >(B1, Fb, s2, ln, hq, rw);

    float* o = out + (size_t)blockIdx.x * (NDIM * NDIM);
#pragma unroll
    for (int gg = 0; gg < 4; ++gg) {
        float4 v;
        v.x = g[4 * gg + 0] + c23 * y[4 * gg + 0] + c16 * s2[4 * gg + 0];
        v.y = g[4 * gg + 1] + c23 * y[4 * gg + 1] + c16 * s2[4 * gg + 1];
        v.z = g[4 * gg + 2] + c23 * y[4 * gg + 2] + c16 * s2[4 * gg + 2];
        v.w = g[4 * gg + 3] + c23 * y[4 * gg + 3] + c16 * s2[4 * gg + 3];
        // slot(row,col) holds transposed realization -> store at [col][row] (exact row-major)
        *(float4*)&o[(cw + ln) * 64 + rw + 8 * gg + 4 * hq] = v;
    }
}

// ---------------- host launch ----------------

extern "C" void kernel_launch(void* const* d_in, const int* in_sizes, int n_in,
                              void* d_out, int out_size, void* d_ws, size_t ws_size,
                              hipStream_t stream) {
    const float* rho0 = (const float*)d_in[0];
    const float* Uh   = (const float*)d_in[1];
    const float* U1   = (const float*)d_in[2];
    const float* L0   = (const float*)d_in[3];
    const float* Lh   = (const float*)d_in[4];
    const float* L1   = (const float*)d_in[5];
    float* out = (float*)d_out;
    unsigned short* ws = (unsigned short*)d_ws;   // 9 bf16 64x64 matrices = 73728 B

    int Bn = in_sizes[0] / (NDIM * NDIM);         // 4096

    krk_setup<<<9, 256, 0, stream>>>(Uh, U1, L0, Lh, L1, ws);
    krk_main<<<Bn, 256, 0, stream>>>(rho0, ws, out);
}